// Round 1
// baseline (332.559 us; speedup 1.0000x reference)
//
#include <hip/hip_runtime.h>
#include <cstdint>
#include <cstddef>

// Problem constants (B=4, N=256, D=32, H=512)
#define NB 4
#define NN 256
#define NPROD 577     // 1 compaction + 64 W2F + 512 T-GEMM tasks
#define NGRID 768     // 3 blocks/CU * 256 CU -- all guaranteed resident

typedef __attribute__((ext_vector_type(8))) short short8;    // 8 bf16 (4 VGPRs)
typedef __attribute__((ext_vector_type(4))) float f32x4;     // 16x16 C/D frag
typedef __attribute__((ext_vector_type(16))) float f32x16;   // 32x32 C/D frag

static __device__ __forceinline__ unsigned cvtpk(float a, float b) {
  unsigned r;
  asm("v_cvt_pk_bf16_f32 %0, %1, %2" : "=v"(r) : "v"(a), "v"(b));
  return r;
}
static __device__ __forceinline__ unsigned short f2bf1(float a) {
  return (unsigned short)(cvtpk(a, 0.f) & 0xffffu);
}
static __device__ __forceinline__ short8 pack8(float4 a0, float4 a1) {
  union { unsigned u[4]; short8 s; } r;
  r.u[0] = cvtpk(a0.x, a0.y); r.u[1] = cvtpk(a0.z, a0.w);
  r.u[2] = cvtpk(a1.x, a1.y); r.u[3] = cvtpk(a1.z, a1.w);
  return r.s;
}
static __device__ __forceinline__ int aldx(int* p) {
  return __hip_atomic_load(p, __ATOMIC_RELAXED, __HIP_MEMORY_SCOPE_AGENT);
}

// ctl layout (ints): [0]=producer ticket, [1]=item ticket, [2]=wq-ready flag,
//                    [3]=W2F done count (->64), [4..19]=T row-group count (->32)
__global__ __launch_bounds__(256, 3) void mega(
    const float* __restrict__ z, const float* __restrict__ motif,
    const float* __restrict__ W1, const float* __restrict__ b1,
    const float* __restrict__ W2, const float* __restrict__ b2,
    const float* __restrict__ W3, const float* __restrict__ b3,
    unsigned short* __restrict__ W2F, unsigned short* __restrict__ Tall,
    int* __restrict__ jlist, int* __restrict__ jcnt,
    int* __restrict__ wq, int* __restrict__ wqn,
    int* __restrict__ ctl, float* __restrict__ out) {
  __shared__ unsigned short h1s[64 * 264];   // 33792 B; also aliased as w1s (32 KB)
  __shared__ float red[256];
  __shared__ int s_b;
  __shared__ int itemc[4];
  __shared__ int baseh[4];

  const int tid = threadIdx.x;
  const size_t OUT2 = (size_t)NB * NN * NN;

  // ======================= producer phase (ticketed) =======================
  for (;;) {
    __syncthreads();
    if (tid == 0)
      s_b = __hip_atomic_fetch_add(&ctl[0], 1, __ATOMIC_RELAXED, __HIP_MEMORY_SCOPE_AGENT);
    __syncthreads();
    const int t = s_b;
    if (t >= NPROD) break;

    if (t == 0) {
      // ---- compaction + static work-queue build (gates everything)
      const int cw = tid >> 6, lane = tid & 63;
      int cnt = 0;
      if (cw < NB) {
        #pragma unroll
        for (int ch = 0; ch < 4; ++ch) {
          int j = ch * 64 + lane;
          float m = motif[cw * 256 + j];
          bool alive = (m != 0.f);
          unsigned long long mk = __ballot(alive);
          unsigned long long below = mk & ((1ull << lane) - 1ull);
          int pos = __popcll(below);
          if (alive) jlist[cw * 256 + cnt + pos] = j;
          cnt += __popcll(mk);
        }
        if (lane == 0) {
          jcnt[cw] = cnt;
          itemc[cw] = cnt * ((cnt + 63) >> 6);
        }
      }
      __syncthreads();
      if (tid == 0) {
        int sacc = 0;
        #pragma unroll
        for (int k = 0; k < NB; ++k) { baseh[k] = sacc; sacc += itemc[k]; }
        *wqn = sacc;
      }
      __syncthreads();
      if (cw < NB) {
        const int K = (cnt + 63) >> 6;
        const int base = baseh[cw];
        int rank = 0;
        #pragma unroll
        for (int ch = 0; ch < 4; ++ch) {
          int i = ch * 64 + lane;
          bool alive = (motif[cw * 256 + i] != 0.f);
          unsigned long long mk = __ballot(alive);
          unsigned long long below = mk & ((1ull << lane) - 1ull);
          int pos = __popcll(below);
          if (alive)
            for (int jt2 = 0; jt2 < K; ++jt2)
              wq[base + (rank + pos) * K + jt2] = (cw * 256 + i) * 4 + jt2;
          rank += __popcll(mk);
        }
      }
      __syncthreads();  // drain all waves' stores to L2 before release
      if (tid == 0)
        __hip_atomic_store(&ctl[2], 1, __ATOMIC_RELEASE, __HIP_MEMORY_SCOPE_AGENT);
    } else if (t <= 64) {
      // ---- W2F builder (bf16 B-fragment layout of W2)
      int f8 = (t - 1) * 256 + tid;
      int lane = f8 & 63;
      int nt = (f8 >> 6) & 1, sg = (f8 >> 7) & 3, hc = (f8 >> 9) & 7, wv = (f8 >> 12) & 3;
      int k2 = wv * 64 + nt * 32 + (lane & 31);
      int hb = hc * 64 + sg * 16 + (lane >> 5) * 8;
      float v[8];
      #pragma unroll
      for (int e = 0; e < 8; ++e) v[e] = W2[(hb + e) * 256 + k2];
      uint4 p;
      p.x = cvtpk(v[0], v[1]); p.y = cvtpk(v[2], v[3]);
      p.z = cvtpk(v[4], v[5]); p.w = cvtpk(v[6], v[7]);
      ((uint4*)W2F)[f8] = p;
      __syncthreads();
      if (tid == 0)
        __hip_atomic_fetch_add(&ctl[3], 1, __ATOMIC_RELEASE, __HIP_MEMORY_SCOPE_AGENT);
    } else {
      // ---- T-GEMM: Tall rows [64*mgrp, +64), cols [512*nblk, +512)
      const int idx = t - 65;
      const int nblk = idx >> 4, mgrp = idx & 15;
      const int bibase = mgrp * 64;
      unsigned short* w1s = h1s;   // 32 KB alias

      #pragma unroll
      for (int r = 0; r < 16; ++r) {
        int task = r * 256 + tid;
        int row = task >> 2;
        int hq = task & 3;
        float4 v = *(const float4*)(W1 + (size_t)row * 512 + nblk * 16 + hq * 4);
        int a = row >> 5, c = row & 31;
        int qd = a >> 3, e = a & 7;
        float hv[4] = {v.x, v.y, v.z, v.w};
        #pragma unroll
        for (int vv = 0; vv < 4; ++vv) {
          int hl = hq * 4 + vv;
          int nl = hl * 32 + c;
          int w2i = nl >> 7, r7 = nl & 127;
          int l16i = r7 >> 3, ntc = r7 & 7;
          w1s[((w2i * 8 + ntc) * 64 + qd * 16 + l16i) * 8 + e] = f2bf1(hv[vv]);
        }
      }
      __syncthreads();

      const int w2 = tid >> 6, lane = tid & 63;
      const int qd = lane >> 4, l16 = lane & 15;

      short8 bfr[8];
      #pragma unroll
      for (int nt = 0; nt < 8; ++nt)
        bfr[nt] = *(const short8*)&w1s[((w2 * 8 + nt) * 64 + lane) * 8];

      const int ncol = nblk * 512 + w2 * 128 + l16 * 8;
      #pragma unroll
      for (int mtg = 0; mtg < 2; ++mtg) {
        short8 afr[2];
        #pragma unroll
        for (int mi = 0; mi < 2; ++mi) {
          const float* zr = z + (size_t)(bibase + (mtg * 2 + mi) * 16 + l16) * 32 + qd * 8;
          float4 a0 = *(const float4*)(zr);
          float4 a1 = *(const float4*)(zr + 4);
          afr[mi] = pack8(a0, a1);
        }
        f32x4 d[2][8];
        #pragma unroll
        for (int mi = 0; mi < 2; ++mi)
          #pragma unroll
          for (int nt = 0; nt < 8; ++nt)
            d[mi][nt] = __builtin_amdgcn_mfma_f32_16x16x32_bf16(
                afr[mi], bfr[nt], (f32x4){0.f, 0.f, 0.f, 0.f}, 0, 0, 0);
        #pragma unroll
        for (int mi = 0; mi < 2; ++mi)
          #pragma unroll
          for (int r = 0; r < 4; ++r) {
            int rowbi = bibase + (mtg * 2 + mi) * 16 + qd * 4 + r;
            if (motif[rowbi] != 0.f) {
              uint4 p;
              p.x = cvtpk(d[mi][0][r], d[mi][1][r]);
              p.y = cvtpk(d[mi][2][r], d[mi][3][r]);
              p.z = cvtpk(d[mi][4][r], d[mi][5][r]);
              p.w = cvtpk(d[mi][6][r], d[mi][7][r]);
              *(uint4*)&Tall[(size_t)rowbi * 16384 + ncol] = p;
            }
          }
      }
      __syncthreads();  // drain all waves' stores before release
      if (tid == 0)
        __hip_atomic_fetch_add(&ctl[4 + mgrp], 1, __ATOMIC_RELEASE, __HIP_MEMORY_SCOPE_AGENT);
    }
  }

  // ======================= wait for work queue =======================
  if (tid == 0) {
    while (aldx(&ctl[2]) == 0) __builtin_amdgcn_s_sleep(1);
    asm volatile("" ::: "memory");
    s_b = *wqn;
  }
  __syncthreads();
  const int nq = s_b;

  // ======================= consumer phase (ticketed items) =======================
  for (;;) {
    __syncthreads();
    if (tid == 0)
      s_b = __hip_atomic_fetch_add(&ctl[1], 1, __ATOMIC_RELAXED, __HIP_MEMORY_SCOPE_AGENT);
    __syncthreads();
    const int t = s_b;
    if (t >= nq + 64) break;

    if (t >= nq) {
      // ---- fill duty: constants for masked (bi,j) pairs; 64 chunks x 4096
      const int c = t - nq;
      for (int p = c * 4096 + tid; p < (c + 1) * 4096; p += 256) {
        int bi = p >> 8, j = p & 255, b = bi >> 8;
        if (motif[bi] == 0.f || motif[b * 256 + j] == 0.f) {
          out[p] = 0.5f;
          out[OUT2 + p] = 0.f;
        }
      }
      continue;
    }

    // ---- heavy item (R16 champion body)
    const int item = wq[t];
    const int w = tid >> 6, lane = tid & 63;
    const int quad = lane >> 4, l16 = lane & 15;
    const int L = lane >> 5, c32 = lane & 31;

    const int bi = item >> 2, jt = item & 3;
    const int b = bi >> 8;
    const int cnt = jcnt[b];
    const int slotbase = jt * 64;
    const float mi_v = motif[bi];

    // z frags gathered through jlist (independent of Tall -> before T spin)
    short8 zfr[4];
    #pragma unroll
    for (int nt = 0; nt < 4; ++nt) {
      int slot = slotbase + nt * 16 + l16;
      int sc = slot < cnt ? slot : cnt - 1;
      int jj = jlist[b * 256 + sc] & 255;
      const float* zr = z + (size_t)(b * 256 + jj) * 32 + quad * 8;
      float4 a0 = *(const float4*)(zr);
      float4 a1 = *(const float4*)(zr + 4);
      zfr[nt] = pack8(a0, a1);
    }

    // epilogue constants: this wave owns k2 in [64w, 64w+64)
    float b2v[2], w3v[2];
    #pragma unroll
    for (int nt = 0; nt < 2; ++nt) {
      int k2 = w * 64 + nt * 32 + c32;
      b2v[nt] = b2[k2];
      w3v[nt] = W3[k2];
    }

    // wait for this item's T row-group (32 producer blocks) + W2F (64 blocks)
    if (tid == 0) {
      const int g = bi >> 6;
      while (aldx(&ctl[4 + g]) < 32) __builtin_amdgcn_s_sleep(1);
      while (aldx(&ctl[3]) < 64) __builtin_amdgcn_s_sleep(1);
    }
    __syncthreads();
    asm volatile("" ::: "memory");

    // ALL tfr fragments (both halves) issued up front
    const unsigned short* Tbase = Tall + (size_t)bi * 16384 + (w * 16 + l16) * 32 + quad * 8;
    short8 tfr[8];
    #pragma unroll
    for (int q = 0; q < 8; ++q)
      tfr[q] = *(const short8*)(Tbase + q * 2048);

    f32x16 acc[2][2];
    #pragma unroll
    for (int mt = 0; mt < 2; ++mt)
      #pragma unroll
      for (int nt = 0; nt < 2; ++nt)
        acc[mt][nt] = (f32x16){0.f,0.f,0.f,0.f,0.f,0.f,0.f,0.f,
                               0.f,0.f,0.f,0.f,0.f,0.f,0.f,0.f};

    const unsigned short* Wp = W2F + w * 32768 + lane * 8;
    const float* b1base = b1 + w * 16 + quad * 4;

    #pragma unroll
    for (int half = 0; half < 2; ++half) {
      // ---- phase 1: wave w fills h-rows {q*64 + w*16 + [0,16)} x 64 slots
      #pragma unroll
      for (int q = 0; q < 4; ++q) {
        float4 b1f = *(const float4*)(b1base + (half * 4 + q) * 64);
        f32x4 cin = {b1f.x, b1f.y, b1f.z, b1f.w};
        #pragma unroll
        for (int nt = 0; nt < 4; ++nt) {
          f32x4 d = __builtin_amdgcn_mfma_f32_16x16x32_bf16(
              tfr[half * 4 + q], zfr[nt], cin, 0, 0, 0);
          uint2 p;
          p.x = cvtpk(fmaxf(d[0], 0.f), fmaxf(d[1], 0.f));
          p.y = cvtpk(fmaxf(d[2], 0.f), fmaxf(d[3], 0.f));
          *(uint2*)&h1s[(nt * 16 + l16) * 264 + q * 64 + w * 16 + quad * 4] = p;
        }
      }
      __syncthreads();

      // ---- phase 2: 16 u-steps; bf 3-deep, af 2-deep
      const unsigned short* Wh = Wp + half * 16384;
      const unsigned short* h1r = &h1s[c32 * 264 + L * 8];
      short8 bfp[3][2], afp[2][2];
      #pragma unroll
      for (int p = 0; p < 3; ++p) {
        bfp[p][0] = *(const short8*)(Wh + p * 1024);
        bfp[p][1] = *(const short8*)(Wh + p * 1024 + 512);
      }
      afp[0][0] = *(const short8*)(h1r);
      afp[0][1] = *(const short8*)(h1r + 32 * 264);
      afp[1][0] = *(const short8*)(h1r + 16);
      afp[1][1] = *(const short8*)(h1r + 32 * 264 + 16);
      #pragma unroll
      for (int u = 0; u < 16; ++u) {
        const int cur = u & 1, bq = u % 3;
        short8 a0 = afp[cur][0], a1 = afp[cur][1];
        short8 b0 = bfp[bq][0], b1q = bfp[bq][1];
        if (u < 14) {
          afp[cur][0] = *(const short8*)(h1r + (u + 2) * 16);
          afp[cur][1] = *(const short8*)(h1r + 32 * 264 + (u + 2) * 16);
        }
        if (u < 13) {
          bfp[bq][0] = *(const short8*)(Wh + (u + 3) * 1024);
          bfp[bq][1] = *(const short8*)(Wh + (u + 3) * 1024 + 512);
        }
        acc[0][0] = __builtin_amdgcn_mfma_f32_32x32x16_bf16(a0, b0, acc[0][0], 0, 0, 0);
        acc[0][1] = __builtin_amdgcn_mfma_f32_32x32x16_bf16(a0, b1q, acc[0][1], 0, 0, 0);
        acc[1][0] = __builtin_amdgcn_mfma_f32_32x32x16_bf16(a1, b0, acc[1][0], 0, 0, 0);
        acc[1][1] = __builtin_amdgcn_mfma_f32_32x32x16_bf16(a1, b1q, acc[1][1], 0, 0, 0);
      }
      if (half == 0) __syncthreads();   // protect h1s before half-1 overwrites
    }

    // ---- epilogue: relu(h2+b2) . W3, reduce over k2, then 4 waves
    float pr[2][16];
    #pragma unroll
    for (int mt = 0; mt < 2; ++mt)
      #pragma unroll
      for (int reg = 0; reg < 16; ++reg) {
        float s = 0.f;
        #pragma unroll
        for (int nt = 0; nt < 2; ++nt) {
          float v = acc[mt][nt][reg] + b2v[nt];
          v = v > 0.f ? v : 0.f;
          s += v * w3v[nt];
        }
        s += __shfl_xor(s, 1);
        s += __shfl_xor(s, 2);
        s += __shfl_xor(s, 4);
        s += __shfl_xor(s, 8);
        s += __shfl_xor(s, 16);
        pr[mt][reg] = s;
      }
    if (c32 == 0) {
      #pragma unroll
      for (int mt = 0; mt < 2; ++mt)
        #pragma unroll
        for (int g = 0; g < 4; ++g) {
          float4 vv = {pr[mt][g * 4 + 0], pr[mt][g * 4 + 1],
                       pr[mt][g * 4 + 2], pr[mt][g * 4 + 3]};
          *(float4*)&red[w * 64 + mt * 32 + g * 8 + L * 4] = vv;
        }
    }
    __syncthreads();
    if (tid < 64) {
      int slot = slotbase + tid;
      if (slot < cnt) {
        int j = jlist[b * 256 + slot] & 255;
        float logit = red[tid] + red[64 + tid] + red[128 + tid] + red[192 + tid] + b3[0];
        float mm = mi_v * motif[b * 256 + j];
        logit *= mm;
        float map = 1.f / (1.f + expf(-logit));
        size_t idx = (size_t)bi * 256 + j;
        out[idx] = map;
        out[OUT2 + idx] = logit;
      }
    }
  }
}

// ---------------------------------------------------------------------------
extern "C" void kernel_launch(void* const* d_in, const int* in_sizes, int n_in,
                              void* d_out, int out_size, void* d_ws, size_t ws_size,
                              hipStream_t stream) {
  const float* z     = (const float*)d_in[0];
  const float* motif = (const float*)d_in[1];
  // d_in[2] residue_mask: all-ones, unused by the reference computation
  const float* W1 = (const float*)d_in[3];
  const float* b1 = (const float*)d_in[4];
  const float* W2 = (const float*)d_in[5];
  const float* b2 = (const float*)d_in[6];
  const float* W3 = (const float*)d_in[7];
  const float* b3 = (const float*)d_in[8];
  float* out = (float*)d_out;

  char* ws = (char*)d_ws;
  unsigned short* Tall = (unsigned short*)ws;                       // 32 MiB
  unsigned short* W2F  = (unsigned short*)(ws + 33554432);          // 256 KiB
  int* jlist = (int*)(ws + 33554432 + 262144);                      // 4 KiB
  int* jcnt  = (int*)(ws + 33554432 + 262144 + 4096);               // 64 B
  int* wq    = (int*)(ws + 33554432 + 262144 + 4096 + 64);          // 16 KiB
  int* wqn   = (int*)(ws + 33554432 + 262144 + 4096 + 64 + 16384);  // 256 B (own lines)
  int* ctl   = (int*)(ws + 33554432 + 262144 + 4096 + 64 + 16384 + 256);  // 128 B

  hipMemsetAsync(ctl, 0, 128, stream);
  mega<<<NGRID, 256, 0, stream>>>(z, motif, W1, b1, W2, b2, W3, b3,
                                  W2F, Tall, jlist, jcnt, wq, wqn, ctl, out);
}

// Round 2
// 163.541 us; speedup vs baseline: 2.0335x; 2.0335x over previous
//
#include <hip/hip_runtime.h>
#include <hip/hip_bf16.h>
#include <cstdint>
#include <cstddef>

// Problem constants (B=4, N=256, D=32, H=512)
#define NB 4
#define NN 256
#define DD 32
#define HH 512

typedef __attribute__((ext_vector_type(8))) short short8;    // 8 bf16 (4 VGPRs) — MFMA A/B frag
typedef __attribute__((ext_vector_type(4))) float f32x4;     // 16x16 C/D frag
typedef __attribute__((ext_vector_type(16))) float f32x16;   // 32x32 C/D frag

// HW packed fp32->bf16 (RNE). a -> low 16, b -> high 16.
static __device__ __forceinline__ unsigned cvtpk(float a, float b) {
  unsigned r;
  asm("v_cvt_pk_bf16_f32 %0, %1, %2" : "=v"(r) : "v"(a), "v"(b));
  return r;
}
static __device__ __forceinline__ unsigned short f2bf1(float a) {
  return (unsigned short)(cvtpk(a, 0.f) & 0xffffu);
}

// build a bf16 A/B frag from 8 consecutive fp32 (two float4 loads already done)
static __device__ __forceinline__ short8 pack8(float4 a0, float4 a1) {
  union { unsigned u[4]; short8 s; } r;
  r.u[0] = cvtpk(a0.x, a0.y); r.u[1] = cvtpk(a0.z, a0.w);
  r.u[2] = cvtpk(a1.x, a1.y); r.u[3] = cvtpk(a1.z, a1.w);
  return r.s;
}

// ---------------------------------------------------------------------------
// prep (grid 577x256):
//  blk < 512 : T-GEMM block; Tall stores predicated on motif[bi]!=0.
//  blk < 576 : W2F builder.
//  blk ==576 : j-compaction + static work-queue build.
// (fill duty moved to fused's idle blocks)
// ---------------------------------------------------------------------------
__global__ __launch_bounds__(256) void prep(const float* __restrict__ z,
                                            const float* __restrict__ W1,
                                            const float* __restrict__ W2,
                                            const float* __restrict__ motif,
                                            unsigned short* __restrict__ W2F,
                                            unsigned short* __restrict__ Tall,
                                            int* __restrict__ jlist,
                                            int* __restrict__ jcnt,
                                            int* __restrict__ wq,
                                            int* __restrict__ wqn) {
  const int blk = blockIdx.x;
  const int tid = threadIdx.x;
  if (blk < 512) {
    __shared__ unsigned short w1s[16384];   // 32 KB: [w2][nt][lane][e]
    const int nblk = blk >> 4, mgrp = blk & 15;
    const int bibase = mgrp * 64;

    #pragma unroll
    for (int r = 0; r < 16; ++r) {
      int task = r * 256 + tid;
      int row = task >> 2;                  // dd = a*32 + c   (0..1023)
      int hq = task & 3;                    // which 4-float group of the 16 h
      float4 v = *(const float4*)(W1 + (size_t)row * 512 + nblk * 16 + hq * 4);
      int a = row >> 5, c = row & 31;
      int quad = a >> 3, e = a & 7;
      float hv[4] = {v.x, v.y, v.z, v.w};
      #pragma unroll
      for (int vv = 0; vv < 4; ++vv) {
        int hl = hq * 4 + vv;
        int nl = hl * 32 + c;               // n_local in [0,512)
        int w2 = nl >> 7, r7 = nl & 127;
        int l16 = r7 >> 3, nt = r7 & 7;
        w1s[((w2 * 8 + nt) * 64 + quad * 16 + l16) * 8 + e] = f2bf1(hv[vv]);
      }
    }
    __syncthreads();

    const int w2 = tid >> 6, lane = tid & 63;
    const int quad = lane >> 4, l16 = lane & 15;

    short8 bfr[8];
    #pragma unroll
    for (int nt = 0; nt < 8; ++nt)
      bfr[nt] = *(const short8*)&w1s[((w2 * 8 + nt) * 64 + lane) * 8];

    const int ncol = nblk * 512 + w2 * 128 + l16 * 8;
    #pragma unroll
    for (int mtg = 0; mtg < 2; ++mtg) {
      short8 afr[2];
      #pragma unroll
      for (int mi = 0; mi < 2; ++mi) {
        const float* zr = z + (size_t)(bibase + (mtg * 2 + mi) * 16 + l16) * 32 + quad * 8;
        float4 a0 = *(const float4*)(zr);
        float4 a1 = *(const float4*)(zr + 4);
        afr[mi] = pack8(a0, a1);
      }
      f32x4 d[2][8];
      #pragma unroll
      for (int mi = 0; mi < 2; ++mi)
        #pragma unroll
        for (int nt = 0; nt < 8; ++nt)
          d[mi][nt] = __builtin_amdgcn_mfma_f32_16x16x32_bf16(
              afr[mi], bfr[nt], (f32x4){0.f, 0.f, 0.f, 0.f}, 0, 0, 0);
      #pragma unroll
      for (int mi = 0; mi < 2; ++mi)
        #pragma unroll
        for (int r = 0; r < 4; ++r) {
          int rowbi = bibase + (mtg * 2 + mi) * 16 + quad * 4 + r;
          if (motif[rowbi] != 0.f) {        // masked rows never read by fused
            uint4 p;
            p.x = cvtpk(d[mi][0][r], d[mi][1][r]);
            p.y = cvtpk(d[mi][2][r], d[mi][3][r]);
            p.z = cvtpk(d[mi][4][r], d[mi][5][r]);
            p.w = cvtpk(d[mi][6][r], d[mi][7][r]);
            *(uint4*)&Tall[(size_t)rowbi * 16384 + ncol] = p;
          }
        }
    }
  } else if (blk < 576) {
    int f8 = (blk - 512) * 256 + tid;       // frag-slot index (8 elems each)
    int lane = f8 & 63;
    int nt = (f8 >> 6) & 1, s = (f8 >> 7) & 3, hc = (f8 >> 9) & 7, w = (f8 >> 12) & 3;
    int k2 = w * 64 + nt * 32 + (lane & 31);
    int hb = hc * 64 + s * 16 + (lane >> 5) * 8;
    float v[8];
    #pragma unroll
    for (int e = 0; e < 8; ++e) v[e] = W2[(hb + e) * 256 + k2];
    uint4 p;
    p.x = cvtpk(v[0], v[1]); p.y = cvtpk(v[2], v[3]);
    p.z = cvtpk(v[4], v[5]); p.w = cvtpk(v[6], v[7]);
    ((uint4*)W2F)[f8] = p;
  } else {
    // ---- compaction + queue build: wave w handles batch b = w
    __shared__ int itemc[4];
    __shared__ int baseh[4];
    const int w = tid >> 6, lane = tid & 63;
    int cnt = 0;
    if (w < NB) {
      #pragma unroll
      for (int ch = 0; ch < 4; ++ch) {
        int j = ch * 64 + lane;
        float m = motif[w * 256 + j];
        bool alive = (m != 0.f);
        unsigned long long mk = __ballot(alive);
        unsigned long long below = mk & ((1ull << lane) - 1ull);
        int pos = __popcll(below);
        if (alive) jlist[w * 256 + cnt + pos] = j;
        cnt += __popcll(mk);
      }
      if (lane == 0) {
        jcnt[w] = cnt;
        itemc[w] = cnt * ((cnt + 63) >> 6);
      }
    }
    __syncthreads();
    if (tid == 0) {
      int s = 0;
      #pragma unroll
      for (int k = 0; k < NB; ++k) { baseh[k] = s; s += itemc[k]; }
      *wqn = s;
    }
    __syncthreads();
    if (w < NB) {
      const int K = (cnt + 63) >> 6;
      const int base = baseh[w];
      int rank = 0;
      #pragma unroll
      for (int ch = 0; ch < 4; ++ch) {
        int i = ch * 64 + lane;
        bool alive = (motif[w * 256 + i] != 0.f);
        unsigned long long mk = __ballot(alive);
        unsigned long long below = mk & ((1ull << lane) - 1ull);
        int pos = __popcll(below);
        if (alive)
          for (int jt = 0; jt < K; ++jt)
            wq[base + (rank + pos) * K + jt] = (w * 256 + i) * 4 + jt;
        rank += __popcll(mk);
      }
    }
  }
}

// ---------------------------------------------------------------------------
// fused: static work queue, one item per 256-thread block (R16 champion body)
// + all 8 tfr fragments hoisted to item start + idle blocks absorb fill.
// Round-2 change: phase-2 software pipeline deepened — bfp (W2F/L2) 3->6-deep,
// afp (LDS) 2->4-deep — to cover ~200+ cyc L2-hit latency that 3-deep (~150cy
// of issue) did not. launch_bounds(256,4) caps VGPR at 128 to hold occupancy.
// ---------------------------------------------------------------------------
__global__ __launch_bounds__(256, 4) void fused(const unsigned short* __restrict__ Tall,
                                             const unsigned short* __restrict__ W2F,
                                             const float* __restrict__ z,
                                             const float* __restrict__ b1,
                                             const float* __restrict__ b2,
                                             const float* __restrict__ W3,
                                             const float* __restrict__ b3,
                                             const float* __restrict__ motif,
                                             const int* __restrict__ jlist,
                                             const int* __restrict__ jcnt,
                                             const int* __restrict__ wq,
                                             const int* __restrict__ wqn,
                                             float* __restrict__ out) {
  __shared__ unsigned short h1s[64 * 264];   // [slot][h_local], stride 264
  __shared__ float red[256];

  const int bx = blockIdx.x;
  const int tid = threadIdx.x;
  const size_t OUT2 = (size_t)NB * NN * NN;
  const int nq = *wqn;

  if (bx >= nq) {
    // ---- fill duty: constants for masked (bi,j) pairs, grid-stride
    const int nf = (int)gridDim.x - nq;
    for (int p = (bx - nq) * 256 + tid; p < NB * NN * NN; p += nf * 256) {
      int bi = p >> 8, j = p & 255, b = bi >> 8;
      if (motif[bi] == 0.f || motif[b * 256 + j] == 0.f) {
        out[p] = 0.5f;
        out[OUT2 + p] = 0.f;
      }
    }
    return;
  }
  const int item = wq[bx];

  const int w = tid >> 6, lane = tid & 63;
  const int quad = lane >> 4, l16 = lane & 15;
  const int L = lane >> 5, c32 = lane & 31;

  const int bi = item >> 2, jt = item & 3;
  const int b = bi >> 8;
  const int cnt = jcnt[b];
  const int slotbase = jt * 64;
  const float mi_v = motif[bi];

  // ALL tfr fragments (both halves) issued up front — one HBM round trip
  const unsigned short* Tbase = Tall + (size_t)bi * 16384 + (w * 16 + l16) * 32 + quad * 8;
  short8 tfr[8];
  #pragma unroll
  for (int q = 0; q < 8; ++q)
    tfr[q] = *(const short8*)(Tbase + q * 2048);

  // phase-1 z frags gathered through jlist
  short8 zfr[4];
  #pragma unroll
  for (int nt = 0; nt < 4; ++nt) {
    int slot = slotbase + nt * 16 + l16;
    int sc = slot < cnt ? slot : cnt - 1;
    int jj = jlist[b * 256 + sc] & 255;
    const float* zr = z + (size_t)(b * 256 + jj) * 32 + quad * 8;
    float4 a0 = *(const float4*)(zr);
    float4 a1 = *(const float4*)(zr + 4);
    zfr[nt] = pack8(a0, a1);
  }

  // epilogue constants: this wave owns k2 in [64w, 64w+64)
  float b2v[2], w3v[2];
  #pragma unroll
  for (int nt = 0; nt < 2; ++nt) {
    int k2 = w * 64 + nt * 32 + c32;
    b2v[nt] = b2[k2];
    w3v[nt] = W3[k2];
  }

  f32x16 acc[2][2];
  #pragma unroll
  for (int mt = 0; mt < 2; ++mt)
    #pragma unroll
    for (int nt = 0; nt < 2; ++nt)
      acc[mt][nt] = (f32x16){0.f,0.f,0.f,0.f,0.f,0.f,0.f,0.f,
                             0.f,0.f,0.f,0.f,0.f,0.f,0.f,0.f};

  const unsigned short* Wp = W2F + w * 32768 + lane * 8;
  const float* b1base = b1 + w * 16 + quad * 4;

  #pragma unroll
  for (int half = 0; half < 2; ++half) {
    // ---- phase 1: wave w fills h-rows {q*64 + w*16 + [0,16)} x 64 slots
    #pragma unroll
    for (int q = 0; q < 4; ++q) {
      float4 b1f = *(const float4*)(b1base + (half * 4 + q) * 64);
      f32x4 cin = {b1f.x, b1f.y, b1f.z, b1f.w};
      #pragma unroll
      for (int nt = 0; nt < 4; ++nt) {
        f32x4 d = __builtin_amdgcn_mfma_f32_16x16x32_bf16(
            tfr[half * 4 + q], zfr[nt], cin, 0, 0, 0);
        uint2 p;
        p.x = cvtpk(fmaxf(d[0], 0.f), fmaxf(d[1], 0.f));
        p.y = cvtpk(fmaxf(d[2], 0.f), fmaxf(d[3], 0.f));
        *(uint2*)&h1s[(nt * 16 + l16) * 264 + q * 64 + w * 16 + quad * 4] = p;
      }
    }
    __syncthreads();

    // ---- phase 2: 16 u-steps (h_local = u*16 + L*8); bf 6-deep, af 4-deep
    const unsigned short* Wh = Wp + half * 16384;
    const unsigned short* h1r = &h1s[c32 * 264 + L * 8];
    short8 bfp[6][2], afp[4][2];
    #pragma unroll
    for (int p = 0; p < 6; ++p) {
      bfp[p][0] = *(const short8*)(Wh + p * 1024);
      bfp[p][1] = *(const short8*)(Wh + p * 1024 + 512);
    }
    #pragma unroll
    for (int p = 0; p < 4; ++p) {
      afp[p][0] = *(const short8*)(h1r + p * 16);
      afp[p][1] = *(const short8*)(h1r + 32 * 264 + p * 16);
    }
    #pragma unroll
    for (int u = 0; u < 16; ++u) {
      const int aq = u & 3, bq = u % 6;
      short8 a0 = afp[aq][0], a1 = afp[aq][1];
      short8 b0 = bfp[bq][0], b1q = bfp[bq][1];
      if (u < 12) {
        afp[aq][0] = *(const short8*)(h1r + (u + 4) * 16);
        afp[aq][1] = *(const short8*)(h1r + 32 * 264 + (u + 4) * 16);
      }
      if (u < 10) {
        bfp[bq][0] = *(const short8*)(Wh + (u + 6) * 1024);
        bfp[bq][1] = *(const short8*)(Wh + (u + 6) * 1024 + 512);
      }
      acc[0][0] = __builtin_amdgcn_mfma_f32_32x32x16_bf16(a0, b0, acc[0][0], 0, 0, 0);
      acc[0][1] = __builtin_amdgcn_mfma_f32_32x32x16_bf16(a0, b1q, acc[0][1], 0, 0, 0);
      acc[1][0] = __builtin_amdgcn_mfma_f32_32x32x16_bf16(a1, b0, acc[1][0], 0, 0, 0);
      acc[1][1] = __builtin_amdgcn_mfma_f32_32x32x16_bf16(a1, b1q, acc[1][1], 0, 0, 0);
    }
    if (half == 0) __syncthreads();   // protect h1s before half-1 overwrites
  }

  // ---- epilogue: relu(h2+b2) . W3, reduce over k2 (32 lanes), then 4 waves
  float pr[2][16];
  #pragma unroll
  for (int mt = 0; mt < 2; ++mt)
    #pragma unroll
    for (int reg = 0; reg < 16; ++reg) {
      float s = 0.f;
      #pragma unroll
      for (int nt = 0; nt < 2; ++nt) {
        float v = acc[mt][nt][reg] + b2v[nt];
        v = v > 0.f ? v : 0.f;
        s += v * w3v[nt];
      }
      s += __shfl_xor(s, 1);
      s += __shfl_xor(s, 2);
      s += __shfl_xor(s, 4);
      s += __shfl_xor(s, 8);
      s += __shfl_xor(s, 16);
      pr[mt][reg] = s;
    }
  if (c32 == 0) {
    #pragma unroll
    for (int mt = 0; mt < 2; ++mt)
      #pragma unroll
      for (int g = 0; g < 4; ++g) {
        float4 vv = {pr[mt][g * 4 + 0], pr[mt][g * 4 + 1],
                     pr[mt][g * 4 + 2], pr[mt][g * 4 + 3]};
        *(float4*)&red[w * 64 + mt * 32 + g * 8 + L * 4] = vv;
      }
  }
  __syncthreads();
  if (tid < 64) {
    int slot = slotbase + tid;
    if (slot < cnt) {
      int j = jlist[b * 256 + slot] & 255;
      float logit = red[tid] + red[64 + tid] + red[128 + tid] + red[192 + tid] + b3[0];
      float mm = mi_v * motif[b * 256 + j];
      logit *= mm;
      float map = 1.f / (1.f + expf(-logit));
      size_t idx = (size_t)bi * 256 + j;
      out[idx] = map;
      out[OUT2 + idx] = logit;
    }
  }
}

// ---------------------------------------------------------------------------
extern "C" void kernel_launch(void* const* d_in, const int* in_sizes, int n_in,
                              void* d_out, int out_size, void* d_ws, size_t ws_size,
                              hipStream_t stream) {
  const float* z     = (const float*)d_in[0];
  const float* motif = (const float*)d_in[1];
  // d_in[2] residue_mask: all-ones, unused by the reference computation
  const float* W1 = (const float*)d_in[3];
  const float* b1 = (const float*)d_in[4];
  const float* W2 = (const float*)d_in[5];
  const float* b2 = (const float*)d_in[6];
  const float* W3 = (const float*)d_in[7];
  const float* b3 = (const float*)d_in[8];
  float* out = (float*)d_out;

  char* ws = (char*)d_ws;
  unsigned short* Tall = (unsigned short*)ws;                       // 32 MiB
  unsigned short* W2F  = (unsigned short*)(ws + 33554432);          // 256 KiB
  int* jlist = (int*)(ws + 33554432 + 262144);                      // 4 KiB
  int* jcnt  = (int*)(ws + 33554432 + 262144 + 4096);               // 64 B
  int* wq    = (int*)(ws + 33554432 + 262144 + 4096 + 64);          // 16 KiB
  int* wqn   = (int*)(ws + 33554432 + 262144 + 4096 + 64 + 16384);  // 64 B

  prep<<<577, 256, 0, stream>>>(z, W1, W2, motif, W2F, Tall,
                                jlist, jcnt, wq, wqn);
  fused<<<4096, 256, 0, stream>>>(Tall, W2F, z, b1, b2, W3, b3, motif,
                                  jlist, jcnt, wq, wqn, out);
}

// Round 3
// 150.126 us; speedup vs baseline: 2.2152x; 1.0894x over previous
//
#include <hip/hip_runtime.h>
#include <hip/hip_bf16.h>
#include <cstdint>
#include <cstddef>

// Problem constants (B=4, N=256, D=32, H=512)
#define NB 4
#define NN 256
#define DD 32
#define HH 512

typedef __attribute__((ext_vector_type(8))) short short8;    // 8 bf16 (4 VGPRs) — MFMA A/B frag
typedef __attribute__((ext_vector_type(4))) float f32x4;     // 16x16 C/D frag
typedef __attribute__((ext_vector_type(16))) float f32x16;   // 32x32 C/D frag

// HW packed fp32->bf16 (RNE). a -> low 16, b -> high 16.
static __device__ __forceinline__ unsigned cvtpk(float a, float b) {
  unsigned r;
  asm("v_cvt_pk_bf16_f32 %0, %1, %2" : "=v"(r) : "v"(a), "v"(b));
  return r;
}
static __device__ __forceinline__ unsigned short f2bf1(float a) {
  return (unsigned short)(cvtpk(a, 0.f) & 0xffffu);
}

// build a bf16 A/B frag from 8 consecutive fp32 (two float4 loads already done)
static __device__ __forceinline__ short8 pack8(float4 a0, float4 a1) {
  union { unsigned u[4]; short8 s; } r;
  r.u[0] = cvtpk(a0.x, a0.y); r.u[1] = cvtpk(a0.z, a0.w);
  r.u[2] = cvtpk(a1.x, a1.y); r.u[3] = cvtpk(a1.z, a1.w);
  return r.s;
}

// ---------------------------------------------------------------------------
// prep (grid 577x256):
//  blk < 512 : T-GEMM block; Tall stores predicated on motif[bi]!=0.
//  blk < 576 : W2F builder.
//  blk ==576 : j-compaction + PAIRED work-queue build (one entry per
//              (alive-i, jt-pair)); entry = bi*4 + jp*2, covers slots
//              [jp*128, jp*128+128).
// ---------------------------------------------------------------------------
__global__ __launch_bounds__(256) void prep(const float* __restrict__ z,
                                            const float* __restrict__ W1,
                                            const float* __restrict__ W2,
                                            const float* __restrict__ motif,
                                            unsigned short* __restrict__ W2F,
                                            unsigned short* __restrict__ Tall,
                                            int* __restrict__ jlist,
                                            int* __restrict__ jcnt,
                                            int* __restrict__ wq,
                                            int* __restrict__ wqn) {
  const int blk = blockIdx.x;
  const int tid = threadIdx.x;
  if (blk < 512) {
    __shared__ unsigned short w1s[16384];   // 32 KB: [w2][nt][lane][e]
    const int nblk = blk >> 4, mgrp = blk & 15;
    const int bibase = mgrp * 64;

    #pragma unroll
    for (int r = 0; r < 16; ++r) {
      int task = r * 256 + tid;
      int row = task >> 2;                  // dd = a*32 + c   (0..1023)
      int hq = task & 3;                    // which 4-float group of the 16 h
      float4 v = *(const float4*)(W1 + (size_t)row * 512 + nblk * 16 + hq * 4);
      int a = row >> 5, c = row & 31;
      int quad = a >> 3, e = a & 7;
      float hv[4] = {v.x, v.y, v.z, v.w};
      #pragma unroll
      for (int vv = 0; vv < 4; ++vv) {
        int hl = hq * 4 + vv;
        int nl = hl * 32 + c;               // n_local in [0,512)
        int w2 = nl >> 7, r7 = nl & 127;
        int l16 = r7 >> 3, nt = r7 & 7;
        w1s[((w2 * 8 + nt) * 64 + quad * 16 + l16) * 8 + e] = f2bf1(hv[vv]);
      }
    }
    __syncthreads();

    const int w2 = tid >> 6, lane = tid & 63;
    const int quad = lane >> 4, l16 = lane & 15;

    short8 bfr[8];
    #pragma unroll
    for (int nt = 0; nt < 8; ++nt)
      bfr[nt] = *(const short8*)&w1s[((w2 * 8 + nt) * 64 + lane) * 8];

    const int ncol = nblk * 512 + w2 * 128 + l16 * 8;
    #pragma unroll
    for (int mtg = 0; mtg < 2; ++mtg) {
      short8 afr[2];
      #pragma unroll
      for (int mi = 0; mi < 2; ++mi) {
        const float* zr = z + (size_t)(bibase + (mtg * 2 + mi) * 16 + l16) * 32 + quad * 8;
        float4 a0 = *(const float4*)(zr);
        float4 a1 = *(const float4*)(zr + 4);
        afr[mi] = pack8(a0, a1);
      }
      f32x4 d[2][8];
      #pragma unroll
      for (int mi = 0; mi < 2; ++mi)
        #pragma unroll
        for (int nt = 0; nt < 8; ++nt)
          d[mi][nt] = __builtin_amdgcn_mfma_f32_16x16x32_bf16(
              afr[mi], bfr[nt], (f32x4){0.f, 0.f, 0.f, 0.f}, 0, 0, 0);
      #pragma unroll
      for (int mi = 0; mi < 2; ++mi)
        #pragma unroll
        for (int r = 0; r < 4; ++r) {
          int rowbi = bibase + (mtg * 2 + mi) * 16 + quad * 4 + r;
          if (motif[rowbi] != 0.f) {        // masked rows never read by fused
            uint4 p;
            p.x = cvtpk(d[mi][0][r], d[mi][1][r]);
            p.y = cvtpk(d[mi][2][r], d[mi][3][r]);
            p.z = cvtpk(d[mi][4][r], d[mi][5][r]);
            p.w = cvtpk(d[mi][6][r], d[mi][7][r]);
            *(uint4*)&Tall[(size_t)rowbi * 16384 + ncol] = p;
          }
        }
    }
  } else if (blk < 576) {
    int f8 = (blk - 512) * 256 + tid;       // frag-slot index (8 elems each)
    int lane = f8 & 63;
    int nt = (f8 >> 6) & 1, s = (f8 >> 7) & 3, hc = (f8 >> 9) & 7, w = (f8 >> 12) & 3;
    int k2 = w * 64 + nt * 32 + (lane & 31);
    int hb = hc * 64 + s * 16 + (lane >> 5) * 8;
    float v[8];
    #pragma unroll
    for (int e = 0; e < 8; ++e) v[e] = W2[(hb + e) * 256 + k2];
    uint4 p;
    p.x = cvtpk(v[0], v[1]); p.y = cvtpk(v[2], v[3]);
    p.z = cvtpk(v[4], v[5]); p.w = cvtpk(v[6], v[7]);
    ((uint4*)W2F)[f8] = p;
  } else {
    // ---- compaction + paired queue build: wave w handles batch b = w
    __shared__ int itemc[4];
    __shared__ int baseh[4];
    const int w = tid >> 6, lane = tid & 63;
    int cnt = 0;
    if (w < NB) {
      #pragma unroll
      for (int ch = 0; ch < 4; ++ch) {
        int j = ch * 64 + lane;
        float m = motif[w * 256 + j];
        bool alive = (m != 0.f);
        unsigned long long mk = __ballot(alive);
        unsigned long long below = mk & ((1ull << lane) - 1ull);
        int pos = __popcll(below);
        if (alive) jlist[w * 256 + cnt + pos] = j;
        cnt += __popcll(mk);
      }
      if (lane == 0) {
        int K = (cnt + 63) >> 6;
        jcnt[w] = cnt;
        itemc[w] = cnt * ((K + 1) >> 1);    // one entry per (i, jt-pair)
      }
    }
    __syncthreads();
    if (tid == 0) {
      int s = 0;
      #pragma unroll
      for (int k = 0; k < NB; ++k) { baseh[k] = s; s += itemc[k]; }
      *wqn = s;
    }
    __syncthreads();
    if (w < NB) {
      const int K = (cnt + 63) >> 6;
      const int KP = (K + 1) >> 1;
      const int base = baseh[w];
      int rank = 0;
      #pragma unroll
      for (int ch = 0; ch < 4; ++ch) {
        int i = ch * 64 + lane;
        bool alive = (motif[w * 256 + i] != 0.f);
        unsigned long long mk = __ballot(alive);
        unsigned long long below = mk & ((1ull << lane) - 1ull);
        int pos = __popcll(below);
        if (alive)
          for (int jp = 0; jp < KP; ++jp)
            wq[base + (rank + pos) * KP + jp] = (w * 256 + i) * 4 + jp * 2;
        rank += __popcll(mk);
      }
    }
  }
}

// ---------------------------------------------------------------------------
// fused (round 3): 512-thread / 8-wave blocks; each block = one (bi, jt-pair)
// = M=128 x N=256 x K=512 GEMM. Merging the two jt items of the same bi:
//   - Tall row fetched ONCE per bi (HBM reads halve)
//   - W2F streamed once per 2 items (L2 B-traffic halves)
//   - per-wave u-iter: 1 B-frag (1 KB) feeds 4 MFMAs (4 m-tiles) -> depth-3
//     prefetch covers 2x the latency of the old layout
//   - half the startup pointer-chases and barriers per unit of work
// Waves 0-3: slots 0-63, waves 4-7: slots 64-127 (phase 1); each wave owns a
// 32-wide k2 slice in phase 2 (acc = 4 mt x 16 = 64 VGPR).
// ---------------------------------------------------------------------------
__global__ __launch_bounds__(512) void fused(const unsigned short* __restrict__ Tall,
                                             const unsigned short* __restrict__ W2F,
                                             const float* __restrict__ z,
                                             const float* __restrict__ b1,
                                             const float* __restrict__ b2,
                                             const float* __restrict__ W3,
                                             const float* __restrict__ b3,
                                             const float* __restrict__ motif,
                                             const int* __restrict__ jlist,
                                             const int* __restrict__ jcnt,
                                             const int* __restrict__ wq,
                                             const int* __restrict__ wqn,
                                             float* __restrict__ out) {
  __shared__ unsigned short h1s[128 * 264];  // [slot][h_local(256)+pad], 67.6 KB
  __shared__ float red[1024];                // [wave][row]  4 KB

  const int bx = blockIdx.x;
  const int tid = threadIdx.x;
  const size_t OUT2 = (size_t)NB * NN * NN;
  const int nq = *wqn;

  if (bx >= nq) {
    // ---- fill duty: constants for masked (bi,j) pairs, grid-stride
    const int nf = (int)gridDim.x - nq;
    for (int p = (bx - nq) * 512 + tid; p < NB * NN * NN; p += nf * 512) {
      int bi = p >> 8, j = p & 255, b = bi >> 8;
      if (motif[bi] == 0.f || motif[b * 256 + j] == 0.f) {
        out[p] = 0.5f;
        out[OUT2 + p] = 0.f;
      }
    }
    return;
  }
  const int item = wq[bx];

  const int w = tid >> 6, lane = tid & 63;     // w in [0,8)
  const int quad = lane >> 4, l16 = lane & 15;
  const int L = lane >> 5, c32 = lane & 31;
  const int wv3 = w & 3;                       // tfr/phase-1 col group
  const int hg = (w >> 2) * 64;                // slot-half this wave fills

  const int bi = item >> 2, jp = (item & 3) >> 1;
  const int b = bi >> 8;
  const int cnt = jcnt[b];
  const int slotbase = jp * 128;
  const float mi_v = motif[bi];

  // ALL tfr fragments (both halves) issued up front — one HBM round trip.
  // Wave pairs (w, w+4) read the same rows (same bi) -> L2 hit for the second.
  const unsigned short* Tbase = Tall + (size_t)bi * 16384 + (wv3 * 16 + l16) * 32 + quad * 8;
  short8 tfr[8];
  #pragma unroll
  for (int q = 0; q < 8; ++q)
    tfr[q] = *(const short8*)(Tbase + q * 2048);

  // phase-1 z frags gathered through jlist (this wave's 16-slot groups)
  short8 zfr[4];
  #pragma unroll
  for (int nt = 0; nt < 4; ++nt) {
    int slot = slotbase + hg + nt * 16 + l16;
    int sc = slot < cnt ? slot : cnt - 1;
    int jj = jlist[b * 256 + sc] & 255;
    const float* zr = z + (size_t)(b * 256 + jj) * 32 + quad * 8;
    float4 a0 = *(const float4*)(zr);
    float4 a1 = *(const float4*)(zr + 4);
    zfr[nt] = pack8(a0, a1);
  }

  // epilogue constants: this wave owns k2 slice [32w, 32w+32)
  const int k2 = w * 32 + c32;
  const float b2s = b2[k2];
  const float w3s = W3[k2];

  f32x16 acc[4];
  #pragma unroll
  for (int mt = 0; mt < 4; ++mt)
    acc[mt] = (f32x16){0.f,0.f,0.f,0.f,0.f,0.f,0.f,0.f,
                       0.f,0.f,0.f,0.f,0.f,0.f,0.f,0.f};

  // B base: wave w -> old (w>>1) 64-group, (w&1) 32-half
  const unsigned short* Wp = W2F + (w >> 1) * 32768 + (w & 1) * 512 + lane * 8;
  const float* b1base = b1 + wv3 * 16 + quad * 4;

  #pragma unroll
  for (int half = 0; half < 2; ++half) {
    // ---- phase 1: wave fills h1s rows [hg, hg+64) x 256 h-cols of this half
    #pragma unroll
    for (int q = 0; q < 4; ++q) {
      float4 b1f = *(const float4*)(b1base + (half * 4 + q) * 64);
      f32x4 cin = {b1f.x, b1f.y, b1f.z, b1f.w};
      #pragma unroll
      for (int nt = 0; nt < 4; ++nt) {
        f32x4 d = __builtin_amdgcn_mfma_f32_16x16x32_bf16(
            tfr[half * 4 + q], zfr[nt], cin, 0, 0, 0);
        uint2 p;
        p.x = cvtpk(fmaxf(d[0], 0.f), fmaxf(d[1], 0.f));
        p.y = cvtpk(fmaxf(d[2], 0.f), fmaxf(d[3], 0.f));
        *(uint2*)&h1s[(hg + nt * 16 + l16) * 264 + q * 64 + wv3 * 16 + quad * 4] = p;
      }
    }
    __syncthreads();

    // ---- phase 2: 16 u-steps; 1 B-frag (depth-3) x 4 A-frags (lead-2)
    const unsigned short* Wh = Wp + half * 16384;
    const unsigned short* h1r = &h1s[c32 * 264 + L * 8];
    short8 bfp[3], afp[4][2];
    #pragma unroll
    for (int p = 0; p < 3; ++p)
      bfp[p] = *(const short8*)(Wh + p * 1024);
    #pragma unroll
    for (int mt = 0; mt < 4; ++mt) {
      afp[mt][0] = *(const short8*)(h1r + mt * 32 * 264);
      afp[mt][1] = *(const short8*)(h1r + mt * 32 * 264 + 16);
    }
    #pragma unroll
    for (int u = 0; u < 16; ++u) {
      const int cur = u & 1, bq = u % 3;
      short8 a0 = afp[0][cur], a1 = afp[1][cur], a2 = afp[2][cur], a3 = afp[3][cur];
      short8 bf = bfp[bq];
      if (u < 14) {
        afp[0][cur] = *(const short8*)(h1r + (u + 2) * 16);
        afp[1][cur] = *(const short8*)(h1r + 32 * 264 + (u + 2) * 16);
        afp[2][cur] = *(const short8*)(h1r + 64 * 264 + (u + 2) * 16);
        afp[3][cur] = *(const short8*)(h1r + 96 * 264 + (u + 2) * 16);
      }
      if (u < 13)
        bfp[bq] = *(const short8*)(Wh + (u + 3) * 1024);
      acc[0] = __builtin_amdgcn_mfma_f32_32x32x16_bf16(a0, bf, acc[0], 0, 0, 0);
      acc[1] = __builtin_amdgcn_mfma_f32_32x32x16_bf16(a1, bf, acc[1], 0, 0, 0);
      acc[2] = __builtin_amdgcn_mfma_f32_32x32x16_bf16(a2, bf, acc[2], 0, 0, 0);
      acc[3] = __builtin_amdgcn_mfma_f32_32x32x16_bf16(a3, bf, acc[3], 0, 0, 0);
    }
    if (half == 0) __syncthreads();   // protect h1s before half-1 overwrites
  }

  // ---- epilogue: relu(h2+b2) . W3, reduce over this wave's 32 k2 lanes,
  //      then across 8 waves via red[wave][row]
  float pr[4][16];
  #pragma unroll
  for (int mt = 0; mt < 4; ++mt)
    #pragma unroll
    for (int reg = 0; reg < 16; ++reg) {
      float v = acc[mt][reg] + b2s;
      v = v > 0.f ? v : 0.f;
      float s = v * w3s;
      s += __shfl_xor(s, 1);
      s += __shfl_xor(s, 2);
      s += __shfl_xor(s, 4);
      s += __shfl_xor(s, 8);
      s += __shfl_xor(s, 16);
      pr[mt][reg] = s;
    }
  if (c32 == 0) {
    // rows: mt*32 + g*8 + L*4 + [0,4)  (32x32 C-layout, reg groups of 4)
    #pragma unroll
    for (int mt = 0; mt < 4; ++mt)
      #pragma unroll
      for (int g = 0; g < 4; ++g) {
        float4 vv = {pr[mt][g * 4 + 0], pr[mt][g * 4 + 1],
                     pr[mt][g * 4 + 2], pr[mt][g * 4 + 3]};
        *(float4*)&red[w * 128 + mt * 32 + g * 8 + L * 4] = vv;
      }
  }
  __syncthreads();
  if (tid < 128) {
    int slot = slotbase + tid;
    if (slot < cnt) {
      int j = jlist[b * 256 + slot] & 255;
      float logit = b3[0];
      #pragma unroll
      for (int wv = 0; wv < 8; ++wv) logit += red[wv * 128 + tid];
      float mm = mi_v * motif[b * 256 + j];
      logit *= mm;
      float map = 1.f / (1.f + expf(-logit));
      size_t idx = (size_t)bi * 256 + j;
      out[idx] = map;
      out[OUT2 + idx] = logit;
    }
  }
}

// ---------------------------------------------------------------------------
extern "C" void kernel_launch(void* const* d_in, const int* in_sizes, int n_in,
                              void* d_out, int out_size, void* d_ws, size_t ws_size,
                              hipStream_t stream) {
  const float* z     = (const float*)d_in[0];
  const float* motif = (const float*)d_in[1];
  // d_in[2] residue_mask: all-ones, unused by the reference computation
  const float* W1 = (const float*)d_in[3];
  const float* b1 = (const float*)d_in[4];
  const float* W2 = (const float*)d_in[5];
  const float* b2 = (const float*)d_in[6];
  const float* W3 = (const float*)d_in[7];
  const float* b3 = (const float*)d_in[8];
  float* out = (float*)d_out;

  char* ws = (char*)d_ws;
  unsigned short* Tall = (unsigned short*)ws;                       // 32 MiB
  unsigned short* W2F  = (unsigned short*)(ws + 33554432);          // 256 KiB
  int* jlist = (int*)(ws + 33554432 + 262144);                      // 4 KiB
  int* jcnt  = (int*)(ws + 33554432 + 262144 + 4096);               // 64 B
  int* wq    = (int*)(ws + 33554432 + 262144 + 4096 + 64);          // 16 KiB
  int* wqn   = (int*)(ws + 33554432 + 262144 + 4096 + 64 + 16384);  // 64 B

  prep<<<577, 256, 0, stream>>>(z, W1, W2, motif, W2F, Tall,
                                jlist, jcnt, wq, wqn);
  // worst-case nq = 2048 (all rows alive, K=4 -> KP=2); ~512 in practice
  fused<<<2304, 512, 0, stream>>>(Tall, W2F, z, b1, b2, W3, b3, motif,
                                  jlist, jcnt, wq, wqn, out);
}

// Round 4
// 119.011 us; speedup vs baseline: 2.7943x; 1.2614x over previous
//
#include <hip/hip_runtime.h>
#include <hip/hip_bf16.h>
#include <cstdint>
#include <cstddef>

// Problem constants (B=4, N=256, D=32, H=512)
#define NB 4
#define NN 256
#define DD 32
#define HH 512

typedef __attribute__((ext_vector_type(8))) short short8;    // 8 bf16 (4 VGPRs) — MFMA A/B frag
typedef __attribute__((ext_vector_type(4))) float f32x4;     // 16x16 C/D frag
typedef __attribute__((ext_vector_type(16))) float f32x16;   // 32x32 C/D frag

// HW packed fp32->bf16 (RNE). a -> low 16, b -> high 16.
static __device__ __forceinline__ unsigned cvtpk(float a, float b) {
  unsigned r;
  asm("v_cvt_pk_bf16_f32 %0, %1, %2" : "=v"(r) : "v"(a), "v"(b));
  return r;
}
static __device__ __forceinline__ unsigned short f2bf1(float a) {
  return (unsigned short)(cvtpk(a, 0.f) & 0xffffu);
}

// build a bf16 A/B frag from 8 consecutive fp32 (two float4 loads already done)
static __device__ __forceinline__ short8 pack8(float4 a0, float4 a1) {
  union { unsigned u[4]; short8 s; } r;
  r.u[0] = cvtpk(a0.x, a0.y); r.u[1] = cvtpk(a0.z, a0.w);
  r.u[2] = cvtpk(a1.x, a1.y); r.u[3] = cvtpk(a1.z, a1.w);
  return r.s;
}

// ---------------------------------------------------------------------------
// prep0 (grid 64x256): build W1F — W1 in bf16 B-fragment layout, so T-GEMM
// blocks can stream fragments straight from L2 instead of re-staging W1
// through LDS (the old per-block 32KB staging + barrier).
// Row id (65536 rows of 8 elems): row = (nblk<<11)|(w2<<9)|(nt<<6)|lane.
// W1F[row*8 + e] = bf16(W1[(a*32+c)*512 + nblk*16 + hl]),
//   quad=lane>>4, l16=lane&15, a=quad*8+e, nl=w2*128+l16*8+nt, hl=nl>>5, c=nl&31
// ---------------------------------------------------------------------------
__global__ __launch_bounds__(256) void prep0(const float* __restrict__ W1,
                                             unsigned short* __restrict__ W1F) {
  const int f = blockIdx.x * 256 + threadIdx.x;   // 16384 threads, 4 rows each
  #pragma unroll
  for (int r = 0; r < 4; ++r) {
    int row = r * 16384 + f;
    int lane = row & 63;
    int nt = (row >> 6) & 7, w2 = (row >> 9) & 3, nblk = row >> 11;
    int quad = lane >> 4, l16 = lane & 15;
    int nl = w2 * 128 + l16 * 8 + nt;
    int hl = nl >> 5, c = nl & 31;
    const float* src = W1 + (size_t)(nblk * 16 + hl);
    float v[8];
    #pragma unroll
    for (int e = 0; e < 8; ++e)
      v[e] = src[(size_t)((quad * 8 + e) * 32 + c) * 512];
    uint4 p;
    p.x = cvtpk(v[0], v[1]); p.y = cvtpk(v[2], v[3]);
    p.z = cvtpk(v[4], v[5]); p.w = cvtpk(v[6], v[7]);
    *(uint4*)&W1F[(size_t)row * 8] = p;
  }
}

// ---------------------------------------------------------------------------
// prep1 (grid 641x256):
//  blk < 512 : T-GEMM block streaming W1F frags from L2 (no LDS, no barrier)
//  blk < 576 : W2F builder
//  blk ==576 : j-compaction + work-queue build with XCD pair-swizzle
//  blk < 641 : fill duty (masked-pair constants), moved out of fused
// ---------------------------------------------------------------------------
__global__ __launch_bounds__(256) void prep1(const float* __restrict__ z,
                                             const unsigned short* __restrict__ W1F,
                                             const float* __restrict__ W2,
                                             const float* __restrict__ motif,
                                             unsigned short* __restrict__ W2F,
                                             unsigned short* __restrict__ Tall,
                                             int* __restrict__ jlist,
                                             int* __restrict__ jcnt,
                                             int* __restrict__ wq,
                                             int* __restrict__ wqn,
                                             float* __restrict__ out) {
  const int blk = blockIdx.x;
  const int tid = threadIdx.x;
  if (blk < 512) {
    const int nblk = blk >> 4, mgrp = blk & 15;
    const int bibase = mgrp * 64;
    const int w2 = tid >> 6, lane = tid & 63;
    const int quad = lane >> 4, l16 = lane & 15;

    // B-frags straight from W1F (L2-resident 1MB, shared by all 512 blocks)
    short8 bfr[8];
    #pragma unroll
    for (int nt = 0; nt < 8; ++nt)
      bfr[nt] = *(const short8*)&W1F[(size_t)((((nblk * 4 + w2) * 8) + nt) * 64 + lane) * 8];

    const int ncol = nblk * 512 + w2 * 128 + l16 * 8;
    #pragma unroll
    for (int mtg = 0; mtg < 2; ++mtg) {
      short8 afr[2];
      #pragma unroll
      for (int mi = 0; mi < 2; ++mi) {
        const float* zr = z + (size_t)(bibase + (mtg * 2 + mi) * 16 + l16) * 32 + quad * 8;
        float4 a0 = *(const float4*)(zr);
        float4 a1 = *(const float4*)(zr + 4);
        afr[mi] = pack8(a0, a1);
      }
      f32x4 d[2][8];
      #pragma unroll
      for (int mi = 0; mi < 2; ++mi)
        #pragma unroll
        for (int nt = 0; nt < 8; ++nt)
          d[mi][nt] = __builtin_amdgcn_mfma_f32_16x16x32_bf16(
              afr[mi], bfr[nt], (f32x4){0.f, 0.f, 0.f, 0.f}, 0, 0, 0);
      #pragma unroll
      for (int mi = 0; mi < 2; ++mi)
        #pragma unroll
        for (int r = 0; r < 4; ++r) {
          int rowbi = bibase + (mtg * 2 + mi) * 16 + quad * 4 + r;
          if (motif[rowbi] != 0.f) {        // masked rows never read by fused
            uint4 p;
            p.x = cvtpk(d[mi][0][r], d[mi][1][r]);
            p.y = cvtpk(d[mi][2][r], d[mi][3][r]);
            p.z = cvtpk(d[mi][4][r], d[mi][5][r]);
            p.w = cvtpk(d[mi][6][r], d[mi][7][r]);
            *(uint4*)&Tall[(size_t)rowbi * 16384 + ncol] = p;
          }
        }
    }
  } else if (blk < 576) {
    int f8 = (blk - 512) * 256 + tid;       // frag-slot index (8 elems each)
    int lane = f8 & 63;
    int nt = (f8 >> 6) & 1, s = (f8 >> 7) & 3, hc = (f8 >> 9) & 7, w = (f8 >> 12) & 3;
    int k2 = w * 64 + nt * 32 + (lane & 31);
    int hb = hc * 64 + s * 16 + (lane >> 5) * 8;
    float v[8];
    #pragma unroll
    for (int e = 0; e < 8; ++e) v[e] = W2[(hb + e) * 256 + k2];
    uint4 p;
    p.x = cvtpk(v[0], v[1]); p.y = cvtpk(v[2], v[3]);
    p.z = cvtpk(v[4], v[5]); p.w = cvtpk(v[6], v[7]);
    ((uint4*)W2F)[f8] = p;
  } else if (blk == 576) {
    // ---- compaction + queue build: wave w handles batch b = w
    __shared__ int itemc[4];
    __shared__ int baseh[4];
    const int w = tid >> 6, lane = tid & 63;
    int cnt = 0;
    if (w < NB) {
      #pragma unroll
      for (int ch = 0; ch < 4; ++ch) {
        int j = ch * 64 + lane;
        float m = motif[w * 256 + j];
        bool alive = (m != 0.f);
        unsigned long long mk = __ballot(alive);
        unsigned long long below = mk & ((1ull << lane) - 1ull);
        int pos = __popcll(below);
        if (alive) jlist[w * 256 + cnt + pos] = j;
        cnt += __popcll(mk);
      }
      if (lane == 0) {
        jcnt[w] = cnt;
        itemc[w] = cnt * ((cnt + 63) >> 6);
      }
    }
    __syncthreads();
    if (tid == 0) {
      int s = 0;
      #pragma unroll
      for (int k = 0; k < NB; ++k) { baseh[k] = s; s += itemc[k]; }
      *wqn = s;
    }
    __syncthreads();
    if (w < NB) {
      const int K = (cnt + 63) >> 6;
      const int base = baseh[w];
      const int L2n = cnt * K;
      int rank = 0;
      #pragma unroll
      for (int ch = 0; ch < 4; ++ch) {
        int i = ch * 64 + lane;
        bool alive = (motif[w * 256 + i] != 0.f);
        unsigned long long mk = __ballot(alive);
        unsigned long long below = mk & ((1ull << lane) - 1ull);
        int pos = __popcll(below);
        if (alive) {
          int idx0 = (rank + pos) * K;
          for (int jt = 0; jt < K; ++jt) {
            int idx = idx0 + jt;
            int nidx = idx;
            // XCD pair-locality: for K==2, place the two items of one bi
            // 8 apart so round-robin block->XCD puts them on the same XCD
            // (second Tall-row read becomes an L2 hit, not a 2nd HBM fetch).
            if (K == 2) {
              int g = idx >> 4;
              if (g * 16 + 16 <= L2n)
                nidx = g * 16 + ((idx & 1) << 3) + ((idx >> 1) & 7);
            }
            wq[base + nidx] = (w * 256 + i) * 4 + jt;
          }
        }
        rank += __popcll(mk);
      }
    }
  } else {
    // ---- fill duty: constants for masked (bi,j) pairs; 64 blocks x 4096
    const size_t OUT2 = (size_t)NB * NN * NN;
    const int c = blk - 577;
    for (int p = c * 4096 + tid; p < (c + 1) * 4096; p += 256) {
      int bi = p >> 8, j = p & 255, b = bi >> 8;
      if (motif[bi] == 0.f || motif[b * 256 + j] == 0.f) {
        out[p] = 0.5f;
        out[OUT2 + p] = 0.f;
      }
    }
  }
}

// ---------------------------------------------------------------------------
// fused: static work queue, one item per 256-thread block (R0 champion body).
// Round-4 edits vs R0: (1) fill duty moved to prep1 -> idle blocks return
// immediately; (2) B-frag prefetch deepened 3->4 (bq = u&3), no reg cap.
// ---------------------------------------------------------------------------
__global__ __launch_bounds__(256) void fused(const unsigned short* __restrict__ Tall,
                                             const unsigned short* __restrict__ W2F,
                                             const float* __restrict__ z,
                                             const float* __restrict__ b1,
                                             const float* __restrict__ b2,
                                             const float* __restrict__ W3,
                                             const float* __restrict__ b3,
                                             const float* __restrict__ motif,
                                             const int* __restrict__ jlist,
                                             const int* __restrict__ jcnt,
                                             const int* __restrict__ wq,
                                             const int* __restrict__ wqn,
                                             float* __restrict__ out) {
  __shared__ unsigned short h1s[64 * 264];   // [slot][h_local], stride 264
  __shared__ float red[256];

  const int bx = blockIdx.x;
  const int tid = threadIdx.x;
  const size_t OUT2 = (size_t)NB * NN * NN;
  const int nq = *wqn;

  if (bx >= nq) return;                      // fill handled by prep1
  const int item = wq[bx];

  const int w = tid >> 6, lane = tid & 63;
  const int quad = lane >> 4, l16 = lane & 15;
  const int L = lane >> 5, c32 = lane & 31;

  const int bi = item >> 2, jt = item & 3;
  const int b = bi >> 8;
  const int cnt = jcnt[b];
  const int slotbase = jt * 64;
  const float mi_v = motif[bi];

  // ALL tfr fragments (both halves) issued up front — one HBM round trip
  const unsigned short* Tbase = Tall + (size_t)bi * 16384 + (w * 16 + l16) * 32 + quad * 8;
  short8 tfr[8];
  #pragma unroll
  for (int q = 0; q < 8; ++q)
    tfr[q] = *(const short8*)(Tbase + q * 2048);

  // phase-1 z frags gathered through jlist
  short8 zfr[4];
  #pragma unroll
  for (int nt = 0; nt < 4; ++nt) {
    int slot = slotbase + nt * 16 + l16;
    int sc = slot < cnt ? slot : cnt - 1;
    int jj = jlist[b * 256 + sc] & 255;
    const float* zr = z + (size_t)(b * 256 + jj) * 32 + quad * 8;
    float4 a0 = *(const float4*)(zr);
    float4 a1 = *(const float4*)(zr + 4);
    zfr[nt] = pack8(a0, a1);
  }

  // epilogue constants: this wave owns k2 in [64w, 64w+64)
  float b2v[2], w3v[2];
  #pragma unroll
  for (int nt = 0; nt < 2; ++nt) {
    int k2 = w * 64 + nt * 32 + c32;
    b2v[nt] = b2[k2];
    w3v[nt] = W3[k2];
  }

  f32x16 acc[2][2];
  #pragma unroll
  for (int mt = 0; mt < 2; ++mt)
    #pragma unroll
    for (int nt = 0; nt < 2; ++nt)
      acc[mt][nt] = (f32x16){0.f,0.f,0.f,0.f,0.f,0.f,0.f,0.f,
                             0.f,0.f,0.f,0.f,0.f,0.f,0.f,0.f};

  const unsigned short* Wp = W2F + w * 32768 + lane * 8;
  const float* b1base = b1 + w * 16 + quad * 4;

  #pragma unroll
  for (int half = 0; half < 2; ++half) {
    // ---- phase 1: wave w fills h-rows {q*64 + w*16 + [0,16)} x 64 slots
    #pragma unroll
    for (int q = 0; q < 4; ++q) {
      float4 b1f = *(const float4*)(b1base + (half * 4 + q) * 64);
      f32x4 cin = {b1f.x, b1f.y, b1f.z, b1f.w};
      #pragma unroll
      for (int nt = 0; nt < 4; ++nt) {
        f32x4 d = __builtin_amdgcn_mfma_f32_16x16x32_bf16(
            tfr[half * 4 + q], zfr[nt], cin, 0, 0, 0);
        uint2 p;
        p.x = cvtpk(fmaxf(d[0], 0.f), fmaxf(d[1], 0.f));
        p.y = cvtpk(fmaxf(d[2], 0.f), fmaxf(d[3], 0.f));
        *(uint2*)&h1s[(nt * 16 + l16) * 264 + q * 64 + w * 16 + quad * 4] = p;
      }
    }
    __syncthreads();

    // ---- phase 2: 16 u-steps (h_local = u*16 + L*8); bf 4-deep, af 2-deep
    const unsigned short* Wh = Wp + half * 16384;
    const unsigned short* h1r = &h1s[c32 * 264 + L * 8];
    short8 bfp[4][2], afp[2][2];
    #pragma unroll
    for (int p = 0; p < 4; ++p) {
      bfp[p][0] = *(const short8*)(Wh + p * 1024);
      bfp[p][1] = *(const short8*)(Wh + p * 1024 + 512);
    }
    afp[0][0] = *(const short8*)(h1r);
    afp[0][1] = *(const short8*)(h1r + 32 * 264);
    afp[1][0] = *(const short8*)(h1r + 16);
    afp[1][1] = *(const short8*)(h1r + 32 * 264 + 16);
    #pragma unroll
    for (int u = 0; u < 16; ++u) {
      const int cur = u & 1, bq = u & 3;
      short8 a0 = afp[cur][0], a1 = afp[cur][1];
      short8 b0 = bfp[bq][0], b1q = bfp[bq][1];
      if (u < 14) {
        afp[cur][0] = *(const short8*)(h1r + (u + 2) * 16);
        afp[cur][1] = *(const short8*)(h1r + 32 * 264 + (u + 2) * 16);
      }
      if (u < 12) {
        bfp[bq][0] = *(const short8*)(Wh + (u + 4) * 1024);
        bfp[bq][1] = *(const short8*)(Wh + (u + 4) * 1024 + 512);
      }
      acc[0][0] = __builtin_amdgcn_mfma_f32_32x32x16_bf16(a0, b0, acc[0][0], 0, 0, 0);
      acc[0][1] = __builtin_amdgcn_mfma_f32_32x32x16_bf16(a0, b1q, acc[0][1], 0, 0, 0);
      acc[1][0] = __builtin_amdgcn_mfma_f32_32x32x16_bf16(a1, b0, acc[1][0], 0, 0, 0);
      acc[1][1] = __builtin_amdgcn_mfma_f32_32x32x16_bf16(a1, b1q, acc[1][1], 0, 0, 0);
    }
    if (half == 0) __syncthreads();   // protect h1s before half-1 overwrites
  }

  // ---- epilogue: relu(h2+b2) . W3, reduce over k2 (32 lanes), then 4 waves
  float pr[2][16];
  #pragma unroll
  for (int mt = 0; mt < 2; ++mt)
    #pragma unroll
    for (int reg = 0; reg < 16; ++reg) {
      float s = 0.f;
      #pragma unroll
      for (int nt = 0; nt < 2; ++nt) {
        float v = acc[mt][nt][reg] + b2v[nt];
        v = v > 0.f ? v : 0.f;
        s += v * w3v[nt];
      }
      s += __shfl_xor(s, 1);
      s += __shfl_xor(s, 2);
      s += __shfl_xor(s, 4);
      s += __shfl_xor(s, 8);
      s += __shfl_xor(s, 16);
      pr[mt][reg] = s;
    }
  if (c32 == 0) {
    #pragma unroll
    for (int mt = 0; mt < 2; ++mt)
      #pragma unroll
      for (int g = 0; g < 4; ++g) {
        float4 vv = {pr[mt][g * 4 + 0], pr[mt][g * 4 + 1],
                     pr[mt][g * 4 + 2], pr[mt][g * 4 + 3]};
        *(float4*)&red[w * 64 + mt * 32 + g * 8 + L * 4] = vv;
      }
  }
  __syncthreads();
  if (tid < 64) {
    int slot = slotbase + tid;
    if (slot < cnt) {
      int j = jlist[b * 256 + slot] & 255;
      float logit = red[tid] + red[64 + tid] + red[128 + tid] + red[192 + tid] + b3[0];
      float mm = mi_v * motif[b * 256 + j];
      logit *= mm;
      float map = 1.f / (1.f + expf(-logit));
      size_t idx = (size_t)bi * 256 + j;
      out[idx] = map;
      out[OUT2 + idx] = logit;
    }
  }
}

// ---------------------------------------------------------------------------
extern "C" void kernel_launch(void* const* d_in, const int* in_sizes, int n_in,
                              void* d_out, int out_size, void* d_ws, size_t ws_size,
                              hipStream_t stream) {
  const float* z     = (const float*)d_in[0];
  const float* motif = (const float*)d_in[1];
  // d_in[2] residue_mask: all-ones, unused by the reference computation
  const float* W1 = (const float*)d_in[3];
  const float* b1 = (const float*)d_in[4];
  const float* W2 = (const float*)d_in[5];
  const float* b2 = (const float*)d_in[6];
  const float* W3 = (const float*)d_in[7];
  const float* b3 = (const float*)d_in[8];
  float* out = (float*)d_out;

  char* ws = (char*)d_ws;
  unsigned short* Tall = (unsigned short*)ws;                            // 32 MiB
  unsigned short* W2F  = (unsigned short*)(ws + 33554432);               // 256 KiB
  unsigned short* W1F  = (unsigned short*)(ws + 33554432 + 262144);      // 1 MiB
  char* tail = ws + 33554432 + 262144 + 1048576;
  int* jlist = (int*)(tail);                                             // 4 KiB
  int* jcnt  = (int*)(tail + 4096);                                      // 64 B
  int* wq    = (int*)(tail + 4096 + 64);                                 // 16 KiB
  int* wqn   = (int*)(tail + 4096 + 64 + 16384);                         // 64 B

  prep0<<<64, 256, 0, stream>>>(W1, W1F);
  prep1<<<641, 256, 0, stream>>>(z, W1F, W2, motif, W2F, Tall,
                                 jlist, jcnt, wq, wqn, out);
  fused<<<4096, 256, 0, stream>>>(Tall, W2F, z, b1, b2, W3, b3, motif,
                                  jlist, jcnt, wq, wqn, out);
}